// Round 8
// baseline (86.974 us; speedup 1.0000x reference)
//
#include <hip/hip_runtime.h>
#include <math.h>

typedef float f32x4 __attribute__((ext_vector_type(4)));

// ---- workspace layout (float offsets) ----
#define NSLOT    8
#define WS_E     0                        // 512: e (last row, layer 2 out)
#define WS_E1    512                      // 512: layer-1 activations
#define WS_HPRE  1024                     // NSLOT*512 partial accumulators
#define WS_VAL   (WS_HPRE + NSLOT*512)    // 512: per-row 0.5*z^2+sp terms
#define WS_CNT   (WS_VAL + 512)           // 1 uint completion counter (+15 pad)
#define WS_H     (WS_CNT + 16)            // 512: h
#define WS_T1    (WS_H + 512)             // 512: h@Wmu.T + bmu
#define WS_SP    (WS_T1 + 512)            // 512: h@Wsig.T + bsig (= log sig)
#define WS_AL    (WS_SP + 512)            // 8:   h@Wal.T + bal
#define WS_ZLEN  (NSLOT*512 + 512 + 16)   // zero range starting at WS_HPRE

// ---------------------------------------------------------------------------
// k_e1: e1 = relu(W1 @ cur + b1), one wave per row (128 blocks x 4 waves).
// Also zeroes slots + val + counter (must re-zero every launch).
// ---------------------------------------------------------------------------
__global__ __launch_bounds__(256) void k_e1(const float* __restrict__ X,
    const float* __restrict__ W1, const float* __restrict__ b1,
    float* __restrict__ ws)
{
    int t = threadIdx.x, b = blockIdx.x;
    int w = t >> 6, l = t & 63;
    int r = b * 4 + w;                       // 0..511
    float s = W1[(size_t)r * 64 + l] * X[4094 * 64 + l];
#pragma unroll
    for (int off = 32; off > 0; off >>= 1) s += __shfl_down(s, off);
    if (l == 0) ws[WS_E1 + r] = fmaxf(s + b1[r], 0.f);
    int gid = b * 256 + t;
    if (gid < WS_ZLEN) ws[WS_HPRE + gid] = 0.f;
}

// ---------------------------------------------------------------------------
// k_e2: e = relu(W2 @ e1 + b2), one wave per row (512 blocks). R2-proven.
// ---------------------------------------------------------------------------
__global__ __launch_bounds__(64) void k_e2(const float* __restrict__ W2,
    const float* __restrict__ b2, float* __restrict__ ws)
{
    int r = blockIdx.x, l = threadIdx.x;
    const float4* w4 = (const float4*)(W2 + (size_t)r * 512);
    const float4* x4 = (const float4*)(ws + WS_E1);
    float4 w0 = w4[2*l], w1 = w4[2*l+1];
    float4 x0 = x4[2*l], x1 = x4[2*l+1];
    float s = w0.x*x0.x + w0.y*x0.y + w0.z*x0.z + w0.w*x0.w
            + w1.x*x1.x + w1.y*x1.y + w1.z*x1.z + w1.w*x1.w;
#pragma unroll
    for (int off = 32; off > 0; off >>= 1) s += __shfl_down(s, off);
    if (l == 0) ws[WS_E + r] = fmaxf(s + b2[r], 0.f);
}

// ---------------------------------------------------------------------------
// k_contract: h_pre[j] += sum_{i,d} prev[i]*e[d]*A[i,d,j].  R7-proven loop:
// ballot-compact nonzero e[d] (bit-exact skip), pad nnz to x16 with
// zero-weight rows, depth-8 NONTEMPORAL float4 streaming (8 loads in flight).
// ---------------------------------------------------------------------------
__global__ __launch_bounds__(256) void k_contract(const float* __restrict__ A,
    const float* __restrict__ prev, float* __restrict__ ws)
{
    __shared__ float cvals[160];
    __shared__ unsigned short idxs[160];
    __shared__ int cnts[2];
    __shared__ float comb[512];

    int t = threadIdx.x;
    int b = blockIdx.x;
    int i = b >> 2;
    int d0 = (b & 3) << 7;
    const float* e = ws + WS_E;

    float c = 0.f; bool nz = false;
    if (t < 128) {
        c = prev[i] * e[d0 + t];
        nz = (c != 0.f);
    }
    unsigned long long bm = __ballot(nz);
    int lane = t & 63;
    int w = t >> 6;
    if (t < 128 && lane == 0) cnts[w] = __popcll(bm);
    __syncthreads();
    if (nz) {
        int pos = __popcll(bm & ((1ull << lane) - 1)) + (w ? cnts[0] : 0);
        idxs[pos] = (unsigned short)t;
        cvals[pos] = c;
    }
    int nnz = cnts[0] + cnts[1];
    int nnzp = (nnz + 15) & ~15;
    if (t < 16 && nnz + t < nnzp) {          // zero-weight padding rows
        cvals[nnz + t] = 0.f;
        idxs[nnz + t] = 0;
    }
    __syncthreads();

    int g  = t >> 7;      // wave-uniform: waves {0,1} -> 0; {2,3} -> 1
    int jj = t & 127;     // float4 column index
    const float* Abase = A + ((size_t)i * 512 + d0) * 512 + (size_t)jj * 4;
    f32x4 acc = (f32x4)0.f;

    for (int k = g; k + 14 < nnzp; k += 16) {   // group g: rows k,k+2,...,k+14
        int i0 = idxs[k],    i1 = idxs[k+2],  i2 = idxs[k+4],  i3 = idxs[k+6];
        int i4 = idxs[k+8],  i5 = idxs[k+10], i6 = idxs[k+12], i7 = idxs[k+14];
        float c0 = cvals[k],    c1 = cvals[k+2],  c2 = cvals[k+4],  c3 = cvals[k+6];
        float c4 = cvals[k+8],  c5 = cvals[k+10], c6 = cvals[k+12], c7 = cvals[k+14];
        f32x4 a0 = __builtin_nontemporal_load((const f32x4*)(Abase + ((size_t)i0 << 9)));
        f32x4 a1 = __builtin_nontemporal_load((const f32x4*)(Abase + ((size_t)i1 << 9)));
        f32x4 a2 = __builtin_nontemporal_load((const f32x4*)(Abase + ((size_t)i2 << 9)));
        f32x4 a3 = __builtin_nontemporal_load((const f32x4*)(Abase + ((size_t)i3 << 9)));
        f32x4 a4 = __builtin_nontemporal_load((const f32x4*)(Abase + ((size_t)i4 << 9)));
        f32x4 a5 = __builtin_nontemporal_load((const f32x4*)(Abase + ((size_t)i5 << 9)));
        f32x4 a6 = __builtin_nontemporal_load((const f32x4*)(Abase + ((size_t)i6 << 9)));
        f32x4 a7 = __builtin_nontemporal_load((const f32x4*)(Abase + ((size_t)i7 << 9)));
        acc += c0 * a0; acc += c1 * a1; acc += c2 * a2; acc += c3 * a3;
        acc += c4 * a4; acc += c5 * a5; acc += c6 * a6; acc += c7 * a7;
    }

    if (g == 1) { ((f32x4*)comb)[jj] = acc; }
    __syncthreads();
    if (g == 0) {
        f32x4 o = ((f32x4*)comb)[jj];
        acc += o;
        float* hp = ws + WS_HPRE + (size_t)(b & (NSLOT - 1)) * 512;
        int j = jj * 4;
        atomicAdd(&hp[j],     acc.x);
        atomicAdd(&hp[j + 1], acc.y);
        atomicAdd(&hp[j + 2], acc.z);
        atomicAdd(&hp[j + 3], acc.w);
    }
}

// ---------------------------------------------------------------------------
// k_h: h = sigmoid(sum of slots); writes out[1..512] = h. 8 blocks x 64.
// ---------------------------------------------------------------------------
__global__ __launch_bounds__(64) void k_h(float* __restrict__ ws, float* __restrict__ out)
{
    int j = blockIdx.x * 64 + threadIdx.x;
    float s = 0.f;
#pragma unroll
    for (int s2 = 0; s2 < NSLOT; ++s2) s += ws[WS_HPRE + s2 * 512 + j];
    float h = 1.f / (1.f + expf(-s));
    ws[WS_H + j] = h;
    out[1 + j] = h;
}

// ---------------------------------------------------------------------------
// k_mv3: t1 = Wmu@h+bmu (rows 0..511), sp = Wsig@h+bsig (512..1023),
// al = Wal@h+bal (1024..1031). One wave per row.
// ---------------------------------------------------------------------------
__global__ __launch_bounds__(64) void k_mv3(const float* __restrict__ Wmu, const float* __restrict__ bmu,
    const float* __restrict__ Wsig, const float* __restrict__ bsig,
    const float* __restrict__ Wal, const float* __restrict__ bal,
    float* __restrict__ ws)
{
    int r = blockIdx.x;
    const float* Wrow; float bias; float* outp;
    if (r < 512)       { Wrow = Wmu  + (size_t)r * 512;           bias = bmu[r];           outp = ws + WS_T1 + r; }
    else if (r < 1024) { int rr = r - 512;  Wrow = Wsig + (size_t)rr * 512; bias = bsig[rr]; outp = ws + WS_SP + rr; }
    else               { int rr = r - 1024; Wrow = Wal  + (size_t)rr * 512; bias = bal[rr];  outp = ws + WS_AL + rr; }
    int l = threadIdx.x;
    const float4* W4 = (const float4*)Wrow;
    const float4* h4 = (const float4*)(ws + WS_H);
    float4 w0 = W4[2*l], w1 = W4[2*l+1];
    float4 h0 = h4[2*l], h1 = h4[2*l+1];
    float s = w0.x*h0.x + w0.y*h0.y + w0.z*h0.z + w0.w*h0.w
            + w1.x*h1.x + w1.y*h1.y + w1.z*h1.z + w1.w*h1.w;
#pragma unroll
    for (int off = 32; off > 0; off >>= 1) s += __shfl_down(s, off);
    if (l == 0) *outp = s + bias;
}

// ---------------------------------------------------------------------------
// k_muf = k_mv1 + k_final, 512 blocks x 64 (full width kept). Block r:
// mu[r] = Wmu2[r,:]@t1 + bmu2[r]; val[r] = 0.5*z^2 + sp (plain store, unique
// address). fence + counter; LAST block's wave does 8 deterministic butterfly
// reductions over val[] (coalesced) + logsumexp -> out[0].
// ---------------------------------------------------------------------------
__global__ __launch_bounds__(64) void k_muf(const float* __restrict__ W, const float* __restrict__ bvec,
    const float* __restrict__ X, float* __restrict__ ws, float* __restrict__ out)
{
    int r = blockIdx.x, l = threadIdx.x;
    const float4* W4 = (const float4*)(W + (size_t)r * 512);
    const float4* x4 = (const float4*)(ws + WS_T1);
    float4 w0 = W4[2*l], w1 = W4[2*l+1];
    float4 x0 = x4[2*l], x1 = x4[2*l+1];
    float s = w0.x*x0.x + w0.y*x0.y + w0.z*x0.z + w0.w*x0.w
            + w1.x*x1.x + w1.y*x1.y + w1.z*x1.z + w1.w*x1.w;
#pragma unroll
    for (int off = 32; off > 0; off >>= 1) s += __shfl_down(s, off);
    if (l == 0) {
        float mu = s + bvec[r];
        int x = r & 63;
        float nx = X[4095 * 64 + x];
        float sp = ws[WS_SP + r];
        float z  = (nx - mu) * expf(-sp);
        ws[WS_VAL + r] = 0.5f * z * z + sp;
    }
    __threadfence();
    unsigned int done = 0;
    if (l == 0) done = atomicAdd((unsigned int*)(ws + WS_CNT), 1u);
    done = __shfl(done, 0);
    if (done == 511) {
        __threadfence();
        float lc[8];
#pragma unroll
        for (int m = 0; m < 8; ++m) {
            float v = ws[WS_VAL + m * 64 + l];
#pragma unroll
            for (int off = 32; off > 0; off >>= 1) v += __shfl_xor(v, off);
            lc[m] = -v - 58.812066125099056f;       // 0.5*64*log(2*pi)
        }
        if (l == 0) {
            float al[8], g[8];
            float mx1 = -1e30f, mx2 = -1e30f;
#pragma unroll
            for (int q = 0; q < 8; ++q) {
                al[q] = ws[WS_AL + q];
                g[q]  = al[q] + lc[q];
                mx1 = fmaxf(mx1, al[q]);
                mx2 = fmaxf(mx2, g[q]);
            }
            float s1 = 0.f, s2 = 0.f;
#pragma unroll
            for (int q = 0; q < 8; ++q) { s1 += expf(al[q] - mx1); s2 += expf(g[q] - mx2); }
            out[0] = (mx2 + logf(s2)) - (mx1 + logf(s1));
        }
    }
}

extern "C" void kernel_launch(void* const* d_in, const int* in_sizes, int n_in,
                              void* d_out, int out_size, void* d_ws, size_t ws_size,
                              hipStream_t stream)
{
    const float* X    = (const float*)d_in[0];
    const float* prev = (const float*)d_in[1];
    const float* A    = (const float*)d_in[2];
    const float* W1   = (const float*)d_in[3];
    const float* b1   = (const float*)d_in[4];
    const float* W2   = (const float*)d_in[5];
    const float* b2   = (const float*)d_in[6];
    const float* Wmu  = (const float*)d_in[7];
    const float* bmu  = (const float*)d_in[8];
    const float* Wmu2 = (const float*)d_in[9];
    const float* bmu2 = (const float*)d_in[10];
    const float* Wsig = (const float*)d_in[11];
    const float* bsig = (const float*)d_in[12];
    const float* Wal  = (const float*)d_in[13];
    const float* bal  = (const float*)d_in[14];
    float* out = (float*)d_out;
    float* ws  = (float*)d_ws;

    hipLaunchKernelGGL(k_e1,       dim3(128),  dim3(256), 0, stream, X, W1, b1, ws);
    hipLaunchKernelGGL(k_e2,       dim3(512),  dim3(64),  0, stream, W2, b2, ws);
    hipLaunchKernelGGL(k_contract, dim3(2048), dim3(256), 0, stream, A, prev, ws);
    hipLaunchKernelGGL(k_h,        dim3(8),    dim3(64),  0, stream, ws, out);
    hipLaunchKernelGGL(k_mv3,      dim3(1032), dim3(64),  0, stream, Wmu, bmu, Wsig, bsig, Wal, bal, ws);
    hipLaunchKernelGGL(k_muf,      dim3(512),  dim3(64),  0, stream, Wmu2, bmu2, X, ws, out);
}

// Round 9
// 70.964 us; speedup vs baseline: 1.2256x; 1.2256x over previous
//
#include <hip/hip_runtime.h>
#include <math.h>

typedef float f32x4 __attribute__((ext_vector_type(4)));

// ---- workspace layout (float offsets) ----
#define NSLOT    8
#define WS_E     0                        // 512: e (last row, layer 2 out)
#define WS_E1    512                      // 512: layer-1 activations
#define WS_HPRE  1024                     // NSLOT*512 partial accumulators
#define WS_H     (WS_HPRE + NSLOT*512)    // 512: h
#define WS_T1    (WS_H + 512)             // 512: h@Wmu.T + bmu
#define WS_SP    (WS_T1 + 512)            // 512: h@Wsig.T + bsig (= log sig)
#define WS_MU    (WS_SP + 512)            // 512: mu
#define WS_AL    (WS_MU + 512)            // 8:   h@Wal.T + bal

// ---------------------------------------------------------------------------
// k_e1: e1 = relu(W1 @ cur + b1), one wave per row (128 blocks x 4 waves).
// Also zeroes the NSLOT accumulator slots (must re-zero every launch).
// ---------------------------------------------------------------------------
__global__ __launch_bounds__(256) void k_e1(const float* __restrict__ X,
    const float* __restrict__ W1, const float* __restrict__ b1,
    float* __restrict__ ws)
{
    int t = threadIdx.x, b = blockIdx.x;
    int w = t >> 6, l = t & 63;
    int r = b * 4 + w;                       // 0..511
    float s = W1[(size_t)r * 64 + l] * X[4094 * 64 + l];
#pragma unroll
    for (int off = 32; off > 0; off >>= 1) s += __shfl_down(s, off);
    if (l == 0) ws[WS_E1 + r] = fmaxf(s + b1[r], 0.f);
    int gid = b * 256 + t;
    if (gid < NSLOT * 512) ws[WS_HPRE + gid] = 0.f;
}

// ---------------------------------------------------------------------------
// k_e2: e = relu(W2 @ e1 + b2), one wave per row (512 blocks). R2-proven.
// ---------------------------------------------------------------------------
__global__ __launch_bounds__(64) void k_e2(const float* __restrict__ W2,
    const float* __restrict__ b2, float* __restrict__ ws)
{
    int r = blockIdx.x, l = threadIdx.x;
    const float4* w4 = (const float4*)(W2 + (size_t)r * 512);
    const float4* x4 = (const float4*)(ws + WS_E1);
    float4 w0 = w4[2*l], w1 = w4[2*l+1];
    float4 x0 = x4[2*l], x1 = x4[2*l+1];
    float s = w0.x*x0.x + w0.y*x0.y + w0.z*x0.z + w0.w*x0.w
            + w1.x*x1.x + w1.y*x1.y + w1.z*x1.z + w1.w*x1.w;
#pragma unroll
    for (int off = 32; off > 0; off >>= 1) s += __shfl_down(s, off);
    if (l == 0) ws[WS_E + r] = fmaxf(s + b2[r], 0.f);
}

// ---------------------------------------------------------------------------
// k_contract: h_pre[j] += sum_{i,d} prev[i]*e[d]*A[i,d,j].  R7-proven loop:
// ballot-compact nonzero e[d] (bit-exact skip), pad nnz to x16 with
// zero-weight rows, depth-8 NONTEMPORAL float4 streaming (8 loads in flight).
// ---------------------------------------------------------------------------
__global__ __launch_bounds__(256) void k_contract(const float* __restrict__ A,
    const float* __restrict__ prev, float* __restrict__ ws)
{
    __shared__ float cvals[160];
    __shared__ unsigned short idxs[160];
    __shared__ int cnts[2];
    __shared__ float comb[512];

    int t = threadIdx.x;
    int b = blockIdx.x;
    int i = b >> 2;
    int d0 = (b & 3) << 7;
    const float* e = ws + WS_E;

    float c = 0.f; bool nz = false;
    if (t < 128) {
        c = prev[i] * e[d0 + t];
        nz = (c != 0.f);
    }
    unsigned long long bm = __ballot(nz);
    int lane = t & 63;
    int w = t >> 6;
    if (t < 128 && lane == 0) cnts[w] = __popcll(bm);
    __syncthreads();
    if (nz) {
        int pos = __popcll(bm & ((1ull << lane) - 1)) + (w ? cnts[0] : 0);
        idxs[pos] = (unsigned short)t;
        cvals[pos] = c;
    }
    int nnz = cnts[0] + cnts[1];
    int nnzp = (nnz + 15) & ~15;
    if (t < 16 && nnz + t < nnzp) {          // zero-weight padding rows
        cvals[nnz + t] = 0.f;
        idxs[nnz + t] = 0;
    }
    __syncthreads();

    int g  = t >> 7;      // wave-uniform: waves {0,1} -> 0; {2,3} -> 1
    int jj = t & 127;     // float4 column index
    const float* Abase = A + ((size_t)i * 512 + d0) * 512 + (size_t)jj * 4;
    f32x4 acc = (f32x4)0.f;

    for (int k = g; k + 14 < nnzp; k += 16) {   // group g: rows k,k+2,...,k+14
        int i0 = idxs[k],    i1 = idxs[k+2],  i2 = idxs[k+4],  i3 = idxs[k+6];
        int i4 = idxs[k+8],  i5 = idxs[k+10], i6 = idxs[k+12], i7 = idxs[k+14];
        float c0 = cvals[k],    c1 = cvals[k+2],  c2 = cvals[k+4],  c3 = cvals[k+6];
        float c4 = cvals[k+8],  c5 = cvals[k+10], c6 = cvals[k+12], c7 = cvals[k+14];
        f32x4 a0 = __builtin_nontemporal_load((const f32x4*)(Abase + ((size_t)i0 << 9)));
        f32x4 a1 = __builtin_nontemporal_load((const f32x4*)(Abase + ((size_t)i1 << 9)));
        f32x4 a2 = __builtin_nontemporal_load((const f32x4*)(Abase + ((size_t)i2 << 9)));
        f32x4 a3 = __builtin_nontemporal_load((const f32x4*)(Abase + ((size_t)i3 << 9)));
        f32x4 a4 = __builtin_nontemporal_load((const f32x4*)(Abase + ((size_t)i4 << 9)));
        f32x4 a5 = __builtin_nontemporal_load((const f32x4*)(Abase + ((size_t)i5 << 9)));
        f32x4 a6 = __builtin_nontemporal_load((const f32x4*)(Abase + ((size_t)i6 << 9)));
        f32x4 a7 = __builtin_nontemporal_load((const f32x4*)(Abase + ((size_t)i7 << 9)));
        acc += c0 * a0; acc += c1 * a1; acc += c2 * a2; acc += c3 * a3;
        acc += c4 * a4; acc += c5 * a5; acc += c6 * a6; acc += c7 * a7;
    }

    if (g == 1) { ((f32x4*)comb)[jj] = acc; }
    __syncthreads();
    if (g == 0) {
        f32x4 o = ((f32x4*)comb)[jj];
        acc += o;
        float* hp = ws + WS_HPRE + (size_t)(b & (NSLOT - 1)) * 512;
        int j = jj * 4;
        atomicAdd(&hp[j],     acc.x);
        atomicAdd(&hp[j + 1], acc.y);
        atomicAdd(&hp[j + 2], acc.z);
        atomicAdd(&hp[j + 3], acc.w);
    }
}

// ---------------------------------------------------------------------------
// k_h: h = sigmoid(sum of slots); writes out[1..512] = h.
// ---------------------------------------------------------------------------
__global__ __launch_bounds__(512) void k_h(float* __restrict__ ws, float* __restrict__ out)
{
    int t = threadIdx.x;
    float s = 0.f;
#pragma unroll
    for (int s2 = 0; s2 < NSLOT; ++s2) s += ws[WS_HPRE + s2 * 512 + t];
    float h = 1.f / (1.f + expf(-s));
    ws[WS_H + t] = h;
    out[1 + t] = h;
}

// ---------------------------------------------------------------------------
// k_mv3: t1 = Wmu@h+bmu (rows 0..511), sp = Wsig@h+bsig (512..1023),
// al = Wal@h+bal (1024..1031). One wave per row.
// ---------------------------------------------------------------------------
__global__ __launch_bounds__(64) void k_mv3(const float* __restrict__ Wmu, const float* __restrict__ bmu,
    const float* __restrict__ Wsig, const float* __restrict__ bsig,
    const float* __restrict__ Wal, const float* __restrict__ bal,
    float* __restrict__ ws)
{
    int r = blockIdx.x;
    const float* Wrow; float bias; float* outp;
    if (r < 512)       { Wrow = Wmu  + (size_t)r * 512;           bias = bmu[r];           outp = ws + WS_T1 + r; }
    else if (r < 1024) { int rr = r - 512;  Wrow = Wsig + (size_t)rr * 512; bias = bsig[rr]; outp = ws + WS_SP + rr; }
    else               { int rr = r - 1024; Wrow = Wal  + (size_t)rr * 512; bias = bal[rr];  outp = ws + WS_AL + rr; }
    int l = threadIdx.x;
    const float4* W4 = (const float4*)Wrow;
    const float4* h4 = (const float4*)(ws + WS_H);
    float4 w0 = W4[2*l], w1 = W4[2*l+1];
    float4 h0 = h4[2*l], h1 = h4[2*l+1];
    float s = w0.x*h0.x + w0.y*h0.y + w0.z*h0.z + w0.w*h0.w
            + w1.x*h1.x + w1.y*h1.y + w1.z*h1.z + w1.w*h1.w;
#pragma unroll
    for (int off = 32; off > 0; off >>= 1) s += __shfl_down(s, off);
    if (l == 0) *outp = s + bias;
}

// ---------------------------------------------------------------------------
// k_mv1: mu = Wmu2 @ t1 + bmu2. One wave per row.
// ---------------------------------------------------------------------------
__global__ __launch_bounds__(64) void k_mv1(const float* __restrict__ W, const float* __restrict__ bvec,
    float* __restrict__ ws)
{
    int r = blockIdx.x;
    int l = threadIdx.x;
    const float4* W4 = (const float4*)(W + (size_t)r * 512);
    const float4* x4 = (const float4*)(ws + WS_T1);
    float4 w0 = W4[2*l], w1 = W4[2*l+1];
    float4 x0 = x4[2*l], x1 = x4[2*l+1];
    float s = w0.x*x0.x + w0.y*x0.y + w0.z*x0.z + w0.w*x0.w
            + w1.x*x1.x + w1.y*x1.y + w1.z*x1.z + w1.w*x1.w;
#pragma unroll
    for (int off = 32; off > 0; off >>= 1) s += __shfl_down(s, off);
    if (l == 0) ws[WS_MU + r] = s + bvec[r];
}

// ---------------------------------------------------------------------------
// k_final: mixture log-likelihood, thread t = m*64 + x.
// ---------------------------------------------------------------------------
__global__ __launch_bounds__(512) void k_final(const float* __restrict__ X,
    float* __restrict__ ws, float* __restrict__ out)
{
    __shared__ float lc[8];
    int t = threadIdx.x;
    int m = t >> 6, x = t & 63;
    float nx = X[4095 * 64 + x];
    float mu = ws[WS_MU + t];
    float sp = ws[WS_SP + t];
    float z  = (nx - mu) * expf(-sp);
    float v  = 0.5f * z * z + sp;
#pragma unroll
    for (int off = 32; off > 0; off >>= 1) v += __shfl_down(v, off);
    if (x == 0) lc[m] = -v - 58.812066125099056f;   // 0.5*64*log(2*pi)
    __syncthreads();
    if (t == 0) {
        float al[8], g[8];
        float mx1 = -1e30f, mx2 = -1e30f;
#pragma unroll
        for (int q = 0; q < 8; ++q) {
            al[q] = ws[WS_AL + q];
            g[q]  = al[q] + lc[q];
            mx1 = fmaxf(mx1, al[q]);
            mx2 = fmaxf(mx2, g[q]);
        }
        float s1 = 0.f, s2 = 0.f;
#pragma unroll
        for (int q = 0; q < 8; ++q) { s1 += expf(al[q] - mx1); s2 += expf(g[q] - mx2); }
        out[0] = (mx2 + logf(s2)) - (mx1 + logf(s1));
    }
}

extern "C" void kernel_launch(void* const* d_in, const int* in_sizes, int n_in,
                              void* d_out, int out_size, void* d_ws, size_t ws_size,
                              hipStream_t stream)
{
    const float* X    = (const float*)d_in[0];
    const float* prev = (const float*)d_in[1];
    const float* A    = (const float*)d_in[2];
    const float* W1   = (const float*)d_in[3];
    const float* b1   = (const float*)d_in[4];
    const float* W2   = (const float*)d_in[5];
    const float* b2   = (const float*)d_in[6];
    const float* Wmu  = (const float*)d_in[7];
    const float* bmu  = (const float*)d_in[8];
    const float* Wmu2 = (const float*)d_in[9];
    const float* bmu2 = (const float*)d_in[10];
    const float* Wsig = (const float*)d_in[11];
    const float* bsig = (const float*)d_in[12];
    const float* Wal  = (const float*)d_in[13];
    const float* bal  = (const float*)d_in[14];
    float* out = (float*)d_out;
    float* ws  = (float*)d_ws;

    hipLaunchKernelGGL(k_e1,       dim3(128),  dim3(256), 0, stream, X, W1, b1, ws);
    hipLaunchKernelGGL(k_e2,       dim3(512),  dim3(64),  0, stream, W2, b2, ws);
    hipLaunchKernelGGL(k_contract, dim3(2048), dim3(256), 0, stream, A, prev, ws);
    hipLaunchKernelGGL(k_h,        dim3(1),    dim3(512), 0, stream, ws, out);
    hipLaunchKernelGGL(k_mv3,      dim3(1032), dim3(64),  0, stream, Wmu, bmu, Wsig, bsig, Wal, bal, ws);
    hipLaunchKernelGGL(k_mv1,      dim3(512),  dim3(64),  0, stream, Wmu2, bmu2, ws);
    hipLaunchKernelGGL(k_final,    dim3(1),    dim3(512), 0, stream, X, ws, out);
}